// Round 14
// baseline (278.095 us; speedup 1.0000x reference)
//
#include <hip/hip_runtime.h>

#define DEV __device__ __forceinline__

typedef __attribute__((ext_vector_type(8))) short short8;      // bf16x8 MFMA frag
typedef __attribute__((ext_vector_type(4))) float f32x4;
typedef __attribute__((ext_vector_type(16))) float f32x16;     // 32x32 MFMA C/D
typedef __attribute__((ext_vector_type(4))) unsigned int u32x4;
typedef __attribute__((ext_vector_type(2))) unsigned int u32x2;
typedef __attribute__((ext_vector_type(4))) unsigned short u16x4;

constexpr int Bc = 4, Tc = 2048, Dm = 768, Hh = 12, DK = 64, DFF = 3072;
constexpr int MT = Bc * Tc; // 8192 rows

DEV unsigned short f2bf(float f) {
  unsigned int u = __float_as_uint(f);
  u += 0x7fff + ((u >> 16) & 1);   // RNE
  return (unsigned short)(u >> 16);
}

DEV unsigned cvt_pk_bf16(float lo, float hi) {   // {lo:bf16(lo), hi:bf16(hi)}
  unsigned r;
  asm("v_cvt_pk_bf16_f32 %0, %1, %2" : "=v"(r) : "v"(lo), "v"(hi));
  return r;
}

// tanh-form GELU = v * sigmoid(1.5958(v + 0.044715 v^3)); |err| ~1e-3 << budget
DEV float gelu_fast(float v) {
  float y = 1.5957691216f * (v + 0.044715f * v * v * v);
  return v * (1.0f / (1.0f + __expf(-y)));
}

DEV void gload_lds16(const void* g, void* l) {
  __builtin_amdgcn_global_load_lds(
      (const __attribute__((address_space(1))) void*)g,
      (__attribute__((address_space(3))) void*)l, 16, 0, 0);
}

// ---------------- LayerNorm: fp32 in -> bf16 out, one wave per row ----------
__global__ __launch_bounds__(256) void ln_kernel(const float* __restrict__ x,
    const float* __restrict__ gam, const float* __restrict__ bet,
    unsigned short* __restrict__ out)
{
  int lane = threadIdx.x & 63;
  int row = blockIdx.x * 4 + (threadIdx.x >> 6);
  const float* xr = x + (size_t)row * Dm + lane * 12;
  f32x4 v0 = *(const f32x4*)(xr);
  f32x4 v1 = *(const f32x4*)(xr + 4);
  f32x4 v2 = *(const f32x4*)(xr + 8);
  float s = 0.f, s2 = 0.f;
#pragma unroll
  for (int j = 0; j < 4; j++) {
    s  += v0[j] + v1[j] + v2[j];
    s2 += v0[j]*v0[j] + v1[j]*v1[j] + v2[j]*v2[j];
  }
#pragma unroll
  for (int off = 32; off; off >>= 1) { s += __shfl_xor(s, off); s2 += __shfl_xor(s2, off); }
  float mu = s * (1.f / Dm);
  float inv = rsqrtf(s2 * (1.f / Dm) - mu * mu + 1e-5f);
  int cb = lane * 12;
  unsigned short o[12];
#pragma unroll
  for (int j = 0; j < 4; j++) {
    o[j]     = f2bf((v0[j] - mu) * inv * gam[cb + j]     + bet[cb + j]);
    o[4 + j] = f2bf((v1[j] - mu) * inv * gam[cb + 4 + j] + bet[cb + 4 + j]);
    o[8 + j] = f2bf((v2[j] - mu) * inv * gam[cb + 8 + j] + bet[cb + 8 + j]);
  }
  unsigned short* orow = out + (size_t)row * Dm + cb;
#pragma unroll
  for (int i = 0; i < 3; i++) *(u16x4*)(orow + i * 4) = *(const u16x4*)(&o[i * 4]);
}

// ------- combined weight cast+transpose: 6 weights, one dispatch ------------
__global__ __launch_bounds__(256) void wtrans_all_kernel(
    const float* __restrict__ Wq, const float* __restrict__ Wk,
    const float* __restrict__ Wv, const float* __restrict__ Wo,
    const float* __restrict__ W1, const float* __restrict__ W2,
    unsigned short* wq_t, unsigned short* wk_t, unsigned short* wv_t,
    unsigned short* wo_t, unsigned short* w1_t, unsigned short* w2_t)
{
  __shared__ unsigned short tile[32][33];
  int bid = blockIdx.x;
  const float* src; unsigned short* dst; int K, N, t;
  if (bid < 2304) {
    int w = bid / 576; t = bid % 576; K = Dm; N = Dm;
    src = w == 0 ? Wq : w == 1 ? Wk : w == 2 ? Wv : Wo;
    dst = w == 0 ? wq_t : w == 1 ? wk_t : w == 2 ? wv_t : wo_t;
  } else if (bid < 4608) {
    t = bid - 2304; K = Dm; N = DFF; src = W1; dst = w1_t;
  } else {
    t = bid - 4608; K = DFF; N = Dm; src = W2; dst = w2_t;
  }
  int gx = N / 32;
  int n0 = (t % gx) * 32, k0 = (t / gx) * 32;
  int tx = threadIdx.x & 31, ty = threadIdx.x >> 5;
#pragma unroll
  for (int i = 0; i < 4; i++) {
    int kr = ty * 4 + i;
    tile[kr][tx] = f2bf(src[(size_t)(k0 + kr) * N + n0 + tx]);
  }
  __syncthreads();
#pragma unroll
  for (int i = 0; i < 4; i++) {
    int nr = ty * 4 + i;
    dst[(size_t)(n0 + nr) * K + k0 + tx] = tile[tx][nr];
  }
}

// ------ 128x128 GEMM, 32x32x16 MFMA, 2-phase double-buffered staging --------
// OUT_MODE: 0 f32+resid, 1 bf16 linear, 2 bf16 gelu, 3 bf16 K-head, 4 bf16 V^T
// SWAP: mfma(b,a) -> C^T; lane holds one gm row + 4-consecutive-gn quads.
// 32x32 C/D: col = lane&31, row = (reg&3) + 8*(reg>>2) + 4*(lane>>5).
// Loop: issue STAGE(t+1 -> buf^1) BEFORE computing buf; one __syncthreads()
// per K-step (its vmcnt(0) drain lands the loads that overlapped compute).
template<int OUT_MODE, bool SWAP>
DEV void gemm_body(unsigned short* As, unsigned short* Bs,   // each 2 x 8192
    const unsigned short* __restrict__ A, const unsigned short* __restrict__ Bt,
    const float* __restrict__ bias, const float* __restrict__ resid, void* __restrict__ out,
    int M, int N, int K)
{
  int m0 = blockIdx.x * 128, n0 = blockIdx.y * 128;
  int tid = threadIdx.x, lane = tid & 63, wid = tid >> 6;
  int wr = wid >> 1, wc = wid & 1;
  int r32 = lane & 31, l5 = lane >> 5;
  // hoisted per-lane staging pointers; k0 advance stays scalar
  const unsigned short* pA[4]; const unsigned short* pB[4];
  unsigned short* dA[4]; unsigned short* dB[4];
#pragma unroll
  for (int p = 0; p < 4; p++) {
    int L = wid * 256 + p * 64 + lane;
    int row = L >> 3, pos = L & 7;
    int ch = pos ^ (row & 7);              // inverse chunk-XOR on SOURCE
    pA[p] = A + (size_t)(m0 + row) * K + ch * 8;
    pB[p] = Bt + (size_t)(n0 + row) * K + ch * 8;
    dA[p] = As + (size_t)L * 8;
    dB[p] = Bs + (size_t)L * 8;
  }
  const int nT = K >> 6;
  f32x16 acc[2][2] = {};

#define STAGE_G(c, koff)                                                        \
  {                                                                             \
    _Pragma("unroll")                                                           \
    for (int p = 0; p < 4; p++) {                                               \
      gload_lds16(pA[p] + (koff), dA[p] + (c) * 8192);                          \
      gload_lds16(pB[p] + (koff), dB[p] + (c) * 8192);                          \
    }                                                                           \
  }

  STAGE_G(0, 0)
  __syncthreads();
  int cur = 0;
  for (int t = 0; t < nT; t++) {
    if (t + 1 < nT) STAGE_G(cur ^ 1, (t + 1) * 64)
    const unsigned short* Ac = As + cur * 8192;
    const unsigned short* Bc = Bs + cur * 8192;
#pragma unroll
    for (int kk = 0; kk < 4; kk++) {
      short8 af[2], bfr[2];
#pragma unroll
      for (int g = 0; g < 2; g++) {
        int rowA = wr * 64 + g * 32 + r32;
        af[g]  = *(const short8*)(&Ac[rowA * 64 + (((kk * 2 + l5) ^ (rowA & 7)) << 3)]);
        int rowB = wc * 64 + g * 32 + r32;
        bfr[g] = *(const short8*)(&Bc[rowB * 64 + (((kk * 2 + l5) ^ (rowB & 7)) << 3)]);
      }
#pragma unroll
      for (int mg = 0; mg < 2; mg++)
#pragma unroll
        for (int ng = 0; ng < 2; ng++) {
          if (SWAP)
            acc[mg][ng] = __builtin_amdgcn_mfma_f32_32x32x16_bf16(bfr[ng], af[mg], acc[mg][ng], 0, 0, 0);
          else
            acc[mg][ng] = __builtin_amdgcn_mfma_f32_32x32x16_bf16(af[mg], bfr[ng], acc[mg][ng], 0, 0, 0);
        }
    }
    __syncthreads();   // drains this iter's staged loads; guards buf reuse
    cur ^= 1;
  }
#undef STAGE_G
  if (SWAP) {
    // lane: row gm, cols gn0..gn0+3 per reg-quad
#pragma unroll
    for (int mg = 0; mg < 2; mg++) {
      int gm = m0 + wr * 64 + mg * 32 + r32;
#pragma unroll
      for (int ng = 0; ng < 2; ng++) {
        int nbase = n0 + wc * 64 + ng * 32;
#pragma unroll
        for (int rq = 0; rq < 4; rq++) {
          int gn0 = nbase + rq * 8 + l5 * 4;
          f32x4 v;
#pragma unroll
          for (int rr = 0; rr < 4; rr++) v[rr] = acc[mg][ng][rq * 4 + rr];
          f32x4 bv = *(const f32x4*)(bias + gn0);
#pragma unroll
          for (int rr = 0; rr < 4; rr++) v[rr] += bv[rr];
          if (OUT_MODE == 2) {
#pragma unroll
            for (int rr = 0; rr < 4; rr++) v[rr] = gelu_fast(v[rr]);
          }
          if (OUT_MODE == 0) {
            f32x4 rv = *(const f32x4*)(resid + (size_t)gm * N + gn0);
#pragma unroll
            for (int rr = 0; rr < 4; rr++) v[rr] += rv[rr];
            *(f32x4*)(&((float*)out)[(size_t)gm * N + gn0]) = v;
          } else {
            u32x2 pk;
            pk[0] = cvt_pk_bf16(v[0], v[1]);
            pk[1] = cvt_pk_bf16(v[2], v[3]);
            if (OUT_MODE == 3) {
              int b = gm >> 11, tt = gm & 2047, h = gn0 >> 6, d = gn0 & 63;
              *(u32x2*)(&((unsigned short*)out)[(((size_t)b * Hh + h) * Tc + tt) * DK + d]) = pk;
            } else {
              *(u32x2*)(&((unsigned short*)out)[(size_t)gm * N + gn0]) = pk;
            }
          }
        }
      }
    }
  } else {
    // mode 4 (V^T): lane holds col gn; rows gm0..gm0+3 per reg-quad -> pack along t
#pragma unroll
    for (int mg = 0; mg < 2; mg++) {
#pragma unroll
      for (int ng = 0; ng < 2; ng++) {
        int gn = n0 + wc * 64 + ng * 32 + r32;
        float bv = bias[gn];
        int h = gn >> 6, d = gn & 63;
#pragma unroll
        for (int rq = 0; rq < 4; rq++) {
          int gm0 = m0 + wr * 64 + mg * 32 + rq * 8 + l5 * 4;
          int b = gm0 >> 11, tt = gm0 & 2047;
          u16x4 pk;
#pragma unroll
          for (int rr = 0; rr < 4; rr++) pk[rr] = f2bf(acc[mg][ng][rq * 4 + rr] + bv);
          *(u16x4*)(&((unsigned short*)out)[(((size_t)b * Hh + h) * DK + d) * Tc + tt]) = pk;
        }
      }
    }
  }
}

__global__ __launch_bounds__(256) void gemm_f32out_kernel(const unsigned short* A,
    const unsigned short* Bt, const float* bias, const float* resid, float* out,
    int M, int N, int K)
{
  __shared__ unsigned short As[2 * 128 * 64], Bs[2 * 128 * 64];
  gemm_body<0, true>(As, Bs, A, Bt, bias, resid, out, M, N, K);
}

__global__ __launch_bounds__(256) void gemm_gelu_kernel(const unsigned short* A,
    const unsigned short* Bt, const float* bias, unsigned short* out,
    int M, int N, int K)
{
  __shared__ unsigned short As[2 * 128 * 64], Bs[2 * 128 * 64];
  gemm_body<2, true>(As, Bs, A, Bt, bias, nullptr, out, M, N, K);
}

__global__ __launch_bounds__(256) void gemm_qkv_kernel(const unsigned short* A,
    const unsigned short* Bq, const unsigned short* Bk, const unsigned short* Bv,
    const float* bq, const float* bk, const float* bv,
    unsigned short* oq, unsigned short* okh, unsigned short* ovt)
{
  __shared__ unsigned short As[2 * 128 * 64], Bs[2 * 128 * 64];
  if (blockIdx.z == 0)      gemm_body<1, true >(As, Bs, A, Bq, bq, nullptr, oq,  MT, Dm, Dm);
  else if (blockIdx.z == 1) gemm_body<3, true >(As, Bs, A, Bk, bk, nullptr, okh, MT, Dm, Dm);
  else                      gemm_body<4, false>(As, Bs, A, Bv, bv, nullptr, ovt, MT, Dm, Dm);
}

// ---------------- causal flash attention (unchanged from R11) ---------------
__global__ __launch_bounds__(256) void attn_kernel(const unsigned short* __restrict__ q,
    const unsigned short* __restrict__ kh, const unsigned short* __restrict__ vt,
    unsigned short* __restrict__ o)
{
  __shared__ unsigned short Ks[2][64 * 64], Vs[2][64 * 64];
  __shared__ unsigned short P_lds[4][16 * 64];
  int lane = threadIdx.x & 63, wid = threadIdx.x >> 6;
  int fr = lane & 15, fg = lane >> 4;
  int bid = blockIdx.x;
  int xcd = bid & 7, ii = bid >> 3;          // 8 XCDs x 192 blocks
  int bh = xcd * 6 + (ii >> 5);              // 6 heads per XCD -> K/V fits L2
  int qc = 31 - (ii & 31);                   // longest-first within XCD
  int b = bh / Hh, h = bh - b * Hh;
  int q0 = qc * 64 + wid * 16;
  const size_t qbase = ((size_t)b * Tc) * Dm + h * DK;
  const unsigned short* kg = kh + (size_t)bh * Tc * DK;
  const unsigned short* vg = vt + (size_t)bh * DK * Tc;
  const unsigned short* pK[2]; const unsigned short* pV[2];
  int ldsoff[2];
#pragma unroll
  for (int c = 0; c < 2; c++) {
    int L = c * 256 + wid * 64 + lane;
    int row = L >> 3, cc = (L & 7) ^ (row & 7);
    pK[c] = kg + (size_t)row * DK + cc * 8;
    pV[c] = vg + (size_t)row * Tc + cc * 8;
    ldsoff[c] = L * 8;
  }
  short8 qa0 = *(const short8*)(&q[qbase + (size_t)(q0 + fr) * Dm + fg * 8]);
  short8 qa1 = *(const short8*)(&q[qbase + (size_t)(q0 + fr) * Dm + 32 + fg * 8]);
  f32x4 oa[4] = {};
  f32x4 rs = {};
  short8 onesb;
#pragma unroll
  for (int j = 0; j < 8; j++) onesb[j] = (short)0x3F80;  // bf16 1.0
  unsigned short* Pw = P_lds[wid];
  int nIter = qc + 1;

#define STAGE(buf, kk0)                                                          \
  {                                                                              \
    _Pragma("unroll")                                                            \
    for (int c = 0; c < 2; c++) {                                                \
      gload_lds16(pK[c] + (size_t)(kk0) * DK, &Ks[buf][ldsoff[c]]);              \
      gload_lds16(pV[c] + (kk0),              &Vs[buf][ldsoff[c]]);              \
    }                                                                            \
  }

  STAGE(0, 0)
  for (int it = 0; it < nIter; it++) {
    int cur = it & 1;
    if (it + 1 < nIter) {
      STAGE(cur ^ 1, (it + 1) * 64)
      asm volatile("s_waitcnt vmcnt(4)" ::: "memory");
    } else {
      asm volatile("s_waitcnt vmcnt(0)" ::: "memory");
    }
    __builtin_amdgcn_s_barrier();
    int k0 = it * 64;
    f32x4 st[4];
#pragma unroll
    for (int t = 0; t < 4; t++) {
      int row = t * 16 + fr;
      short8 kf0 = *(const short8*)(&Ks[cur][row * 64 + ((fg)     ^ (fr & 7)) * 8]);
      short8 kf1 = *(const short8*)(&Ks[cur][row * 64 + ((4 + fg) ^ (fr & 7)) * 8]);
      st[t] = {};
      st[t] = __builtin_amdgcn_mfma_f32_16x16x32_bf16(kf0, qa0, st[t], 0, 0, 0);
      st[t] = __builtin_amdgcn_mfma_f32_16x16x32_bf16(kf1, qa1, st[t], 0, 0, 0);
    }
    short8 vb[4][2];
#pragma unroll
    for (int dg = 0; dg < 4; dg++) {
      int row = dg * 16 + fr;
#pragma unroll
      for (int hf = 0; hf < 2; hf++)
        vb[dg][hf] = *(const short8*)(&Vs[cur][row * 64 + ((hf * 4 + fg) ^ (fr & 7)) * 8]);
    }
    bool masked = (it == nIter - 1);
#pragma unroll
    for (int t = 0; t < 4; t++) {
      float p[4];
#pragma unroll
      for (int rr = 0; rr < 4; rr++) {
        float e = __expf(st[t][rr] * 0.125f);
        if (masked) {
          int key = k0 + t * 16 + fg * 4 + rr;
          e = (key <= q0 + fr) ? e : 0.f;
        }
        p[rr] = e;
      }
      u32x2 pkw;
      pkw[0] = cvt_pk_bf16(p[0], p[1]);
      pkw[1] = cvt_pk_bf16(p[2], p[3]);
      int C = t * 2 + (fg >> 1);
      *(u32x2*)(&Pw[fr * 64 + ((C ^ (fr & 7)) << 3) + ((fg & 1) << 2)]) = pkw;
    }
    asm volatile("s_waitcnt lgkmcnt(0)" ::: "memory");
    __builtin_amdgcn_sched_barrier(0);
    short8 pa0 = *(const short8*)(&Pw[fr * 64 + ((fg     ^ (fr & 7)) * 8)]);
    short8 pa1 = *(const short8*)(&Pw[fr * 64 + (((4 + fg) ^ (fr & 7)) * 8)]);
    rs = __builtin_amdgcn_mfma_f32_16x16x32_bf16(pa0, onesb, rs, 0, 0, 0);
    rs = __builtin_amdgcn_mfma_f32_16x16x32_bf16(pa1, onesb, rs, 0, 0, 0);
#pragma unroll
    for (int dg = 0; dg < 4; dg++) {
      oa[dg] = __builtin_amdgcn_mfma_f32_16x16x32_bf16(pa0, vb[dg][0], oa[dg], 0, 0, 0);
      oa[dg] = __builtin_amdgcn_mfma_f32_16x16x32_bf16(pa1, vb[dg][1], oa[dg], 0, 0, 0);
    }
    __builtin_amdgcn_s_barrier();
  }
#undef STAGE
  f32x4 rinv;
#pragma unroll
  for (int rr = 0; rr < 4; rr++) rinv[rr] = __builtin_amdgcn_rcpf(rs[rr]);
#pragma unroll
  for (int dg = 0; dg < 4; dg++)
#pragma unroll
    for (int rr = 0; rr < 4; rr++) {
      int qi = q0 + fg * 4 + rr;
      o[qbase + (size_t)qi * Dm + dg * 16 + fr] = f2bf(oa[dg][rr] * rinv[rr]);
    }
}

// ---------------------------------------------------------------------------
extern "C" void kernel_launch(void* const* d_in, const int* in_sizes, int n_in,
                              void* d_out, int out_size, void* d_ws, size_t ws_size,
                              hipStream_t stream) {
  const float* x     = (const float*)d_in[0];
  const float* ln1_g = (const float*)d_in[2];
  const float* ln1_b = (const float*)d_in[3];
  const float* Wq = (const float*)d_in[4];  const float* bq = (const float*)d_in[5];
  const float* Wk = (const float*)d_in[6];  const float* bk = (const float*)d_in[7];
  const float* Wv = (const float*)d_in[8];  const float* bv = (const float*)d_in[9];
  const float* Wo = (const float*)d_in[10]; const float* bo = (const float*)d_in[11];
  const float* ln2_g = (const float*)d_in[12];
  const float* ln2_b = (const float*)d_in[13];
  const float* W1 = (const float*)d_in[14]; const float* b1 = (const float*)d_in[15];
  const float* W2 = (const float*)d_in[16]; const float* b2 = (const float*)d_in[17];
  float* out = (float*)d_out;

  char* ws = (char*)d_ws;
  const size_t HB = (size_t)MT * Dm * 2;
  unsigned short* h_buf  = (unsigned short*)(ws);
  unsigned short* q_buf  = (unsigned short*)(ws + HB);
  unsigned short* kh_buf = (unsigned short*)(ws + 2 * HB);   // [bh][t][64]
  unsigned short* vt_buf = (unsigned short*)(ws + 3 * HB);   // [bh][d][t]
  unsigned short* wq_t   = (unsigned short*)(ws + 4 * HB);
  unsigned short* wk_t   = wq_t + (size_t)Dm * Dm;
  unsigned short* wv_t   = wk_t + (size_t)Dm * Dm;
  unsigned short* wo_t   = wv_t + (size_t)Dm * Dm;
  unsigned short* w1_t   = wo_t + (size_t)Dm * Dm;
  unsigned short* w2_t   = w1_t + (size_t)Dm * DFF;
  unsigned short* g_buf  = w2_t + (size_t)DFF * Dm;

  wtrans_all_kernel<<<dim3(6912), 256, 0, stream>>>(
      Wq, Wk, Wv, Wo, W1, W2, wq_t, wk_t, wv_t, wo_t, w1_t, w2_t);

  // h = LN1(x)
  ln_kernel<<<MT / 4, 256, 0, stream>>>(x, ln1_g, ln1_b, h_buf);
  // q,k,v = h @ W{q,k,v} + b  (K in [bh][t][64]; V written directly as V^T)
  gemm_qkv_kernel<<<dim3(MT / 128, Dm / 128, 3), 256, 0, stream>>>(
      h_buf, wq_t, wk_t, wv_t, bq, bk, bv, q_buf, kh_buf, vt_buf);
  // attn (into h_buf)
  attn_kernel<<<dim3(1536), 256, 0, stream>>>(q_buf, kh_buf, vt_buf, h_buf);
  // x2 = x + attn @ Wo + bo  (into d_out)
  gemm_f32out_kernel<<<dim3(MT / 128, Dm / 128), 256, 0, stream>>>(
      h_buf, wo_t, bo, x, out, MT, Dm, Dm);
  // h2 = LN2(x2)
  ln_kernel<<<MT / 4, 256, 0, stream>>>(out, ln2_g, ln2_b, h_buf);
  // g = gelu(h2 @ W1 + b1)
  gemm_gelu_kernel<<<dim3(MT / 128, DFF / 128), 256, 0, stream>>>(
      h_buf, w1_t, b1, g_buf, MT, DFF, Dm);
  // out = x2 + g @ W2 + b2
  gemm_f32out_kernel<<<dim3(MT / 128, Dm / 128), 256, 0, stream>>>(
      g_buf, w2_t, b2, out, out, MT, Dm, DFF);
}

// Round 15
// 264.957 us; speedup vs baseline: 1.0496x; 1.0496x over previous
//
#include <hip/hip_runtime.h>

#define DEV __device__ __forceinline__

typedef __attribute__((ext_vector_type(8))) short short8;      // bf16x8 MFMA frag
typedef __attribute__((ext_vector_type(4))) float f32x4;
typedef __attribute__((ext_vector_type(16))) float f32x16;     // 32x32 MFMA C/D
typedef __attribute__((ext_vector_type(4))) unsigned int u32x4;
typedef __attribute__((ext_vector_type(2))) unsigned int u32x2;
typedef __attribute__((ext_vector_type(4))) unsigned short u16x4;

constexpr int Bc = 4, Tc = 2048, Dm = 768, Hh = 12, DK = 64, DFF = 3072;
constexpr int MT = Bc * Tc; // 8192 rows

DEV unsigned short f2bf(float f) {
  unsigned int u = __float_as_uint(f);
  u += 0x7fff + ((u >> 16) & 1);   // RNE
  return (unsigned short)(u >> 16);
}

DEV unsigned cvt_pk_bf16(float lo, float hi) {   // {lo:bf16(lo), hi:bf16(hi)}
  unsigned r;
  asm("v_cvt_pk_bf16_f32 %0, %1, %2" : "=v"(r) : "v"(lo), "v"(hi));
  return r;
}

// tanh-form GELU = v * sigmoid(1.5958(v + 0.044715 v^3)); |err| ~1e-3 << budget
DEV float gelu_fast(float v) {
  float y = 1.5957691216f * (v + 0.044715f * v * v * v);
  return v * (1.0f / (1.0f + __expf(-y)));
}

DEV void gload_lds16(const void* g, void* l) {
  __builtin_amdgcn_global_load_lds(
      (const __attribute__((address_space(1))) void*)g,
      (__attribute__((address_space(3))) void*)l, 16, 0, 0);
}

// ---------------- LayerNorm: fp32 in -> bf16 out, one wave per row ----------
__global__ __launch_bounds__(256) void ln_kernel(const float* __restrict__ x,
    const float* __restrict__ gam, const float* __restrict__ bet,
    unsigned short* __restrict__ out)
{
  int lane = threadIdx.x & 63;
  int row = blockIdx.x * 4 + (threadIdx.x >> 6);
  const float* xr = x + (size_t)row * Dm + lane * 12;
  f32x4 v0 = *(const f32x4*)(xr);
  f32x4 v1 = *(const f32x4*)(xr + 4);
  f32x4 v2 = *(const f32x4*)(xr + 8);
  float s = 0.f, s2 = 0.f;
#pragma unroll
  for (int j = 0; j < 4; j++) {
    s  += v0[j] + v1[j] + v2[j];
    s2 += v0[j]*v0[j] + v1[j]*v1[j] + v2[j]*v2[j];
  }
#pragma unroll
  for (int off = 32; off; off >>= 1) { s += __shfl_xor(s, off); s2 += __shfl_xor(s2, off); }
  float mu = s * (1.f / Dm);
  float inv = rsqrtf(s2 * (1.f / Dm) - mu * mu + 1e-5f);
  int cb = lane * 12;
  unsigned short o[12];
#pragma unroll
  for (int j = 0; j < 4; j++) {
    o[j]     = f2bf((v0[j] - mu) * inv * gam[cb + j]     + bet[cb + j]);
    o[4 + j] = f2bf((v1[j] - mu) * inv * gam[cb + 4 + j] + bet[cb + 4 + j]);
    o[8 + j] = f2bf((v2[j] - mu) * inv * gam[cb + 8 + j] + bet[cb + 8 + j]);
  }
  unsigned short* orow = out + (size_t)row * Dm + cb;
#pragma unroll
  for (int i = 0; i < 3; i++) *(u16x4*)(orow + i * 4) = *(const u16x4*)(&o[i * 4]);
}

// ------- combined weight cast+transpose: 6 weights, one dispatch ------------
__global__ __launch_bounds__(256) void wtrans_all_kernel(
    const float* __restrict__ Wq, const float* __restrict__ Wk,
    const float* __restrict__ Wv, const float* __restrict__ Wo,
    const float* __restrict__ W1, const float* __restrict__ W2,
    unsigned short* wq_t, unsigned short* wk_t, unsigned short* wv_t,
    unsigned short* wo_t, unsigned short* w1_t, unsigned short* w2_t)
{
  __shared__ unsigned short tile[32][33];
  int bid = blockIdx.x;
  const float* src; unsigned short* dst; int K, N, t;
  if (bid < 2304) {
    int w = bid / 576; t = bid % 576; K = Dm; N = Dm;
    src = w == 0 ? Wq : w == 1 ? Wk : w == 2 ? Wv : Wo;
    dst = w == 0 ? wq_t : w == 1 ? wk_t : w == 2 ? wv_t : wo_t;
  } else if (bid < 4608) {
    t = bid - 2304; K = Dm; N = DFF; src = W1; dst = w1_t;
  } else {
    t = bid - 4608; K = DFF; N = Dm; src = W2; dst = w2_t;
  }
  int gx = N / 32;
  int n0 = (t % gx) * 32, k0 = (t / gx) * 32;
  int tx = threadIdx.x & 31, ty = threadIdx.x >> 5;
#pragma unroll
  for (int i = 0; i < 4; i++) {
    int kr = ty * 4 + i;
    tile[kr][tx] = f2bf(src[(size_t)(k0 + kr) * N + n0 + tx]);
  }
  __syncthreads();
#pragma unroll
  for (int i = 0; i < 4; i++) {
    int nr = ty * 4 + i;
    dst[(size_t)(n0 + nr) * K + k0 + tx] = tile[tx][nr];
  }
}

// ------ GEMM, 32x32x16 MFMA, single-buffer staging, tile TM x 128 -----------
// TM=128: 4 waves (2x2), wave tile 64x64.  TM=64: 2 waves (1x2), wave tile
// 64x64, 128 threads — doubles grid for N=768 GEMMs (occupancy fix).
// OUT_MODE: 0 f32+resid, 1 bf16 linear, 2 bf16 gelu, 3 bf16 K-head, 4 bf16 V^T
// SWAP: mfma(b,a) -> C^T; lane holds one gm row + 4-consecutive-gn quads.
// 32x32 C/D: col = lane&31, row = (reg&3) + 8*(reg>>2) + 4*(lane>>5).
template<int OUT_MODE, bool SWAP, int TM>
DEV void gemm_body(unsigned short* As, unsigned short* Bs,
    const unsigned short* __restrict__ A, const unsigned short* __restrict__ Bt,
    const float* __restrict__ bias, const float* __restrict__ resid, void* __restrict__ out,
    int M, int N, int K)
{
  constexpr int NTHR = (TM == 128) ? 256 : 128;
  constexpr int IA = TM * 8 / NTHR;     // A chunk-iters (=4)
  constexpr int IB = 1024 / NTHR;       // B chunk-iters (4 or 8)
  int m0 = blockIdx.x * TM, n0 = blockIdx.y * 128;
  int tid = threadIdx.x, lane = tid & 63, wid = tid >> 6;
  int wr = (TM == 128) ? (wid >> 1) : 0;
  int wc = (TM == 128) ? (wid & 1) : wid;
  int r32 = lane & 31, l5 = lane >> 5;
  // hoisted per-lane staging pointers; k0 advance stays scalar
  const unsigned short* pA[IA]; const unsigned short* pB[IB];
  unsigned short* dA[IA]; unsigned short* dB[IB];
#pragma unroll
  for (int p = 0; p < IA; p++) {
    int L = p * NTHR + tid;            // 16B-chunk id 0..TM*8-1
    int row = L >> 3, pos = L & 7;
    int ch = pos ^ (row & 7);          // inverse chunk-XOR on SOURCE
    pA[p] = A + (size_t)(m0 + row) * K + ch * 8;
    dA[p] = As + (size_t)L * 8;
  }
#pragma unroll
  for (int p = 0; p < IB; p++) {
    int L = p * NTHR + tid;            // 0..1023
    int row = L >> 3, pos = L & 7;
    int ch = pos ^ (row & 7);
    pB[p] = Bt + (size_t)(n0 + row) * K + ch * 8;
    dB[p] = Bs + (size_t)L * 8;
  }
  f32x16 acc[2][2] = {};
  for (int k0 = 0; k0 < K; k0 += 64) {
    __syncthreads();
#pragma unroll
    for (int p = 0; p < IA; p++) gload_lds16(pA[p] + k0, dA[p]);
#pragma unroll
    for (int p = 0; p < IB; p++) gload_lds16(pB[p] + k0, dB[p]);
    __syncthreads();
#pragma unroll
    for (int kk = 0; kk < 4; kk++) {
      short8 af[2], bfr[2];
#pragma unroll
      for (int g = 0; g < 2; g++) {
        int rowA = wr * 64 + g * 32 + r32;
        af[g]  = *(const short8*)(&As[rowA * 64 + (((kk * 2 + l5) ^ (rowA & 7)) << 3)]);
        int rowB = wc * 64 + g * 32 + r32;
        bfr[g] = *(const short8*)(&Bs[rowB * 64 + (((kk * 2 + l5) ^ (rowB & 7)) << 3)]);
      }
#pragma unroll
      for (int mg = 0; mg < 2; mg++)
#pragma unroll
        for (int ng = 0; ng < 2; ng++) {
          if (SWAP)
            acc[mg][ng] = __builtin_amdgcn_mfma_f32_32x32x16_bf16(bfr[ng], af[mg], acc[mg][ng], 0, 0, 0);
          else
            acc[mg][ng] = __builtin_amdgcn_mfma_f32_32x32x16_bf16(af[mg], bfr[ng], acc[mg][ng], 0, 0, 0);
        }
    }
  }
  if (SWAP) {
    // lane: row gm, cols gn0..gn0+3 per reg-quad
#pragma unroll
    for (int mg = 0; mg < 2; mg++) {
      int gm = m0 + wr * 64 + mg * 32 + r32;
#pragma unroll
      for (int ng = 0; ng < 2; ng++) {
        int nbase = n0 + wc * 64 + ng * 32;
#pragma unroll
        for (int rq = 0; rq < 4; rq++) {
          int gn0 = nbase + rq * 8 + l5 * 4;
          f32x4 v;
#pragma unroll
          for (int rr = 0; rr < 4; rr++) v[rr] = acc[mg][ng][rq * 4 + rr];
          f32x4 bv = *(const f32x4*)(bias + gn0);
#pragma unroll
          for (int rr = 0; rr < 4; rr++) v[rr] += bv[rr];
          if (OUT_MODE == 2) {
#pragma unroll
            for (int rr = 0; rr < 4; rr++) v[rr] = gelu_fast(v[rr]);
          }
          if (OUT_MODE == 0) {
            f32x4 rv = *(const f32x4*)(resid + (size_t)gm * N + gn0);
#pragma unroll
            for (int rr = 0; rr < 4; rr++) v[rr] += rv[rr];
            *(f32x4*)(&((float*)out)[(size_t)gm * N + gn0]) = v;
          } else {
            u32x2 pk;
            pk[0] = cvt_pk_bf16(v[0], v[1]);
            pk[1] = cvt_pk_bf16(v[2], v[3]);
            if (OUT_MODE == 3) {
              int b = gm >> 11, tt = gm & 2047, h = gn0 >> 6, d = gn0 & 63;
              *(u32x2*)(&((unsigned short*)out)[(((size_t)b * Hh + h) * Tc + tt) * DK + d]) = pk;
            } else {
              *(u32x2*)(&((unsigned short*)out)[(size_t)gm * N + gn0]) = pk;
            }
          }
        }
      }
    }
  } else {
    // mode 4 (V^T): lane holds col gn; rows gm0..gm0+3 per reg-quad -> pack along t
#pragma unroll
    for (int mg = 0; mg < 2; mg++) {
#pragma unroll
      for (int ng = 0; ng < 2; ng++) {
        int gn = n0 + wc * 64 + ng * 32 + r32;
        float bv = bias[gn];
        int h = gn >> 6, d = gn & 63;
#pragma unroll
        for (int rq = 0; rq < 4; rq++) {
          int gm0 = m0 + wr * 64 + mg * 32 + rq * 8 + l5 * 4;
          int b = gm0 >> 11, tt = gm0 & 2047;
          u16x4 pk;
#pragma unroll
          for (int rr = 0; rr < 4; rr++) pk[rr] = f2bf(acc[mg][ng][rq * 4 + rr] + bv);
          *(u16x4*)(&((unsigned short*)out)[(((size_t)b * Hh + h) * DK + d) * Tc + tt]) = pk;
        }
      }
    }
  }
}

__global__ __launch_bounds__(128) void gemm_f32out_kernel(const unsigned short* A,
    const unsigned short* Bt, const float* bias, const float* resid, float* out,
    int M, int N, int K)
{
  __shared__ unsigned short As[64 * 64], Bs[128 * 64];
  gemm_body<0, true, 64>(As, Bs, A, Bt, bias, resid, out, M, N, K);
}

__global__ __launch_bounds__(256) void gemm_gelu_kernel(const unsigned short* A,
    const unsigned short* Bt, const float* bias, unsigned short* out,
    int M, int N, int K)
{
  __shared__ unsigned short As[128 * 64], Bs[128 * 64];
  gemm_body<2, true, 128>(As, Bs, A, Bt, bias, nullptr, out, M, N, K);
}

__global__ __launch_bounds__(256) void gemm_qkv_kernel(const unsigned short* A,
    const unsigned short* Bq, const unsigned short* Bk, const unsigned short* Bv,
    const float* bq, const float* bk, const float* bv,
    unsigned short* oq, unsigned short* okh, unsigned short* ovt)
{
  __shared__ unsigned short As[128 * 64], Bs[128 * 64];
  if (blockIdx.z == 0)      gemm_body<1, true , 128>(As, Bs, A, Bq, bq, nullptr, oq,  MT, Dm, Dm);
  else if (blockIdx.z == 1) gemm_body<3, true , 128>(As, Bs, A, Bk, bk, nullptr, okh, MT, Dm, Dm);
  else                      gemm_body<4, false, 128>(As, Bs, A, Bv, bv, nullptr, ovt, MT, Dm, Dm);
}

// ---------------- causal flash attention (unchanged from R11) ---------------
__global__ __launch_bounds__(256) void attn_kernel(const unsigned short* __restrict__ q,
    const unsigned short* __restrict__ kh, const unsigned short* __restrict__ vt,
    unsigned short* __restrict__ o)
{
  __shared__ unsigned short Ks[2][64 * 64], Vs[2][64 * 64];
  __shared__ unsigned short P_lds[4][16 * 64];
  int lane = threadIdx.x & 63, wid = threadIdx.x >> 6;
  int fr = lane & 15, fg = lane >> 4;
  int bid = blockIdx.x;
  int xcd = bid & 7, ii = bid >> 3;          // 8 XCDs x 192 blocks
  int bh = xcd * 6 + (ii >> 5);              // 6 heads per XCD -> K/V fits L2
  int qc = 31 - (ii & 31);                   // longest-first within XCD
  int b = bh / Hh, h = bh - b * Hh;
  int q0 = qc * 64 + wid * 16;
  const size_t qbase = ((size_t)b * Tc) * Dm + h * DK;
  const unsigned short* kg = kh + (size_t)bh * Tc * DK;
  const unsigned short* vg = vt + (size_t)bh * DK * Tc;
  const unsigned short* pK[2]; const unsigned short* pV[2];
  int ldsoff[2];
#pragma unroll
  for (int c = 0; c < 2; c++) {
    int L = c * 256 + wid * 64 + lane;
    int row = L >> 3, cc = (L & 7) ^ (row & 7);
    pK[c] = kg + (size_t)row * DK + cc * 8;
    pV[c] = vg + (size_t)row * Tc + cc * 8;
    ldsoff[c] = L * 8;
  }
  short8 qa0 = *(const short8*)(&q[qbase + (size_t)(q0 + fr) * Dm + fg * 8]);
  short8 qa1 = *(const short8*)(&q[qbase + (size_t)(q0 + fr) * Dm + 32 + fg * 8]);
  f32x4 oa[4] = {};
  f32x4 rs = {};
  short8 onesb;
#pragma unroll
  for (int j = 0; j < 8; j++) onesb[j] = (short)0x3F80;  // bf16 1.0
  unsigned short* Pw = P_lds[wid];
  int nIter = qc + 1;

#define STAGE(buf, kk0)                                                          \
  {                                                                              \
    _Pragma("unroll")                                                            \
    for (int c = 0; c < 2; c++) {                                                \
      gload_lds16(pK[c] + (size_t)(kk0) * DK, &Ks[buf][ldsoff[c]]);              \
      gload_lds16(pV[c] + (kk0),              &Vs[buf][ldsoff[c]]);              \
    }                                                                            \
  }

  STAGE(0, 0)
  for (int it = 0; it < nIter; it++) {
    int cur = it & 1;
    if (it + 1 < nIter) {
      STAGE(cur ^ 1, (it + 1) * 64)
      asm volatile("s_waitcnt vmcnt(4)" ::: "memory");
    } else {
      asm volatile("s_waitcnt vmcnt(0)" ::: "memory");
    }
    __builtin_amdgcn_s_barrier();
    int k0 = it * 64;
    f32x4 st[4];
#pragma unroll
    for (int t = 0; t < 4; t++) {
      int row = t * 16 + fr;
      short8 kf0 = *(const short8*)(&Ks[cur][row * 64 + ((fg)     ^ (fr & 7)) * 8]);
      short8 kf1 = *(const short8*)(&Ks[cur][row * 64 + ((4 + fg) ^ (fr & 7)) * 8]);
      st[t] = {};
      st[t] = __builtin_amdgcn_mfma_f32_16x16x32_bf16(kf0, qa0, st[t], 0, 0, 0);
      st[t] = __builtin_amdgcn_mfma_f32_16x16x32_bf16(kf1, qa1, st[t], 0, 0, 0);
    }
    short8 vb[4][2];
#pragma unroll
    for (int dg = 0; dg < 4; dg++) {
      int row = dg * 16 + fr;
#pragma unroll
      for (int hf = 0; hf < 2; hf++)
        vb[dg][hf] = *(const short8*)(&Vs[cur][row * 64 + ((hf * 4 + fg) ^ (fr & 7)) * 8]);
    }
    bool masked = (it == nIter - 1);
#pragma unroll
    for (int t = 0; t < 4; t++) {
      float p[4];
#pragma unroll
      for (int rr = 0; rr < 4; rr++) {
        float e = __expf(st[t][rr] * 0.125f);
        if (masked) {
          int key = k0 + t * 16 + fg * 4 + rr;
          e = (key <= q0 + fr) ? e : 0.f;
        }
        p[rr] = e;
      }
      u32x2 pkw;
      pkw[0] = cvt_pk_bf16(p[0], p[1]);
      pkw[1] = cvt_pk_bf16(p[2], p[3]);
      int C = t * 2 + (fg >> 1);
      *(u32x2*)(&Pw[fr * 64 + ((C ^ (fr & 7)) << 3) + ((fg & 1) << 2)]) = pkw;
    }
    asm volatile("s_waitcnt lgkmcnt(0)" ::: "memory");
    __builtin_amdgcn_sched_barrier(0);
    short8 pa0 = *(const short8*)(&Pw[fr * 64 + ((fg     ^ (fr & 7)) * 8)]);
    short8 pa1 = *(const short8*)(&Pw[fr * 64 + (((4 + fg) ^ (fr & 7)) * 8)]);
    rs = __builtin_amdgcn_mfma_f32_16x16x32_bf16(pa0, onesb, rs, 0, 0, 0);
    rs = __builtin_amdgcn_mfma_f32_16x16x32_bf16(pa1, onesb, rs, 0, 0, 0);
#pragma unroll
    for (int dg = 0; dg < 4; dg++) {
      oa[dg] = __builtin_amdgcn_mfma_f32_16x16x32_bf16(pa0, vb[dg][0], oa[dg], 0, 0, 0);
      oa[dg] = __builtin_amdgcn_mfma_f32_16x16x32_bf16(pa1, vb[dg][1], oa[dg], 0, 0, 0);
    }
    __builtin_amdgcn_s_barrier();
  }
#undef STAGE
  f32x4 rinv;
#pragma unroll
  for (int rr = 0; rr < 4; rr++) rinv[rr] = __builtin_amdgcn_rcpf(rs[rr]);
#pragma unroll
  for (int dg = 0; dg < 4; dg++)
#pragma unroll
    for (int rr = 0; rr < 4; rr++) {
      int qi = q0 + fg * 4 + rr;
      o[qbase + (size_t)qi * Dm + dg * 16 + fr] = f2bf(oa[dg][rr] * rinv[rr]);
    }
}

// ---------------------------------------------------------------------------
extern "C" void kernel_launch(void* const* d_in, const int* in_sizes, int n_in,
                              void* d_out, int out_size, void* d_ws, size_t ws_size,
                              hipStream_t stream) {
  const float* x     = (const float*)d_in[0];
  const float* ln1_g = (const float*)d_in[2];
  const float* ln1_b = (const float*)d_in[3];
  const float* Wq = (const float*)d_in[4];  const float* bq = (const float*)d_in[5];
  const float* Wk = (const float*)d_in[6];  const float* bk = (const float*)d_in[7];
  const float* Wv = (const float*)d_in[8];  const float* bv = (const float*)d_in[9];
  const float* Wo = (const float*)d_in[10]; const float* bo = (const float*)d_in[11];
  const float* ln2_g = (const float*)d_in[12];
  const float* ln2_b = (const float*)d_in[13];
  const float* W1 = (const float*)d_in[14]; const float* b1 = (const float*)d_in[15];
  const float* W2 = (const float*)d_in[16]; const float* b2 = (const float*)d_in[17];
  float* out = (float*)d_out;

  char* ws = (char*)d_ws;
  const size_t HB = (size_t)MT * Dm * 2;
  unsigned short* h_buf  = (unsigned short*)(ws);
  unsigned short* q_buf  = (unsigned short*)(ws + HB);
  unsigned short* kh_buf = (unsigned short*)(ws + 2 * HB);   // [bh][t][64]
  unsigned short* vt_buf = (unsigned short*)(ws + 3 * HB);   // [bh][d][t]
  unsigned short* wq_t   = (unsigned short*)(ws + 4 * HB);
  unsigned short* wk_t   = wq_t + (size_t)Dm * Dm;
  unsigned short* wv_t   = wk_t + (size_t)Dm * Dm;
  unsigned short* wo_t   = wv_t + (size_t)Dm * Dm;
  unsigned short* w1_t   = wo_t + (size_t)Dm * Dm;
  unsigned short* w2_t   = w1_t + (size_t)Dm * DFF;
  unsigned short* g_buf  = w2_t + (size_t)DFF * Dm;

  wtrans_all_kernel<<<dim3(6912), 256, 0, stream>>>(
      Wq, Wk, Wv, Wo, W1, W2, wq_t, wk_t, wv_t, wo_t, w1_t, w2_t);

  // h = LN1(x)
  ln_kernel<<<MT / 4, 256, 0, stream>>>(x, ln1_g, ln1_b, h_buf);
  // q,k,v = h @ W{q,k,v} + b  (K in [bh][t][64]; V written directly as V^T)
  gemm_qkv_kernel<<<dim3(MT / 128, Dm / 128, 3), 256, 0, stream>>>(
      h_buf, wq_t, wk_t, wv_t, bq, bk, bv, q_buf, kh_buf, vt_buf);
  // attn (into h_buf)
  attn_kernel<<<dim3(1536), 256, 0, stream>>>(q_buf, kh_buf, vt_buf, h_buf);
  // x2 = x + attn @ Wo + bo  (into d_out) — TM=64 tiles, 768 blocks
  gemm_f32out_kernel<<<dim3(MT / 64, Dm / 128), 128, 0, stream>>>(
      h_buf, wo_t, bo, x, out, MT, Dm, Dm);
  // h2 = LN2(x2)
  ln_kernel<<<MT / 4, 256, 0, stream>>>(out, ln2_g, ln2_b, h_buf);
  // g = gelu(h2 @ W1 + b1)
  gemm_gelu_kernel<<<dim3(MT / 128, DFF / 128), 256, 0, stream>>>(
      h_buf, w1_t, b1, g_buf, MT, DFF, Dm);
  // out = x2 + g @ W2 + b2 — TM=64 tiles, 768 blocks
  gemm_f32out_kernel<<<dim3(MT / 64, Dm / 128), 128, 0, stream>>>(
      g_buf, w2_t, b2, out, out, MT, Dm, DFF);
}